// Round 1
// baseline (510.575 us; speedup 1.0000x reference)
//
#include <hip/hip_runtime.h>
#include <cstdint>
#include <cstddef>

typedef unsigned short u16;
typedef unsigned int u32;
typedef __attribute__((ext_vector_type(8))) short short8;   // 8 bf16 storage
typedef __attribute__((ext_vector_type(4))) short short4_;  // 4 bf16 storage
typedef __attribute__((ext_vector_type(8))) __bf16 bf16x8;  // MFMA operand
typedef __attribute__((ext_vector_type(4))) float f32x4;

#define BB 2
#define SS 2048
#define DD 2048
#define HH 16
#define HD 128

__device__ __forceinline__ u16 f2bf(float x) {
  u32 u = __float_as_uint(x);
  u32 r = (u + 0x7FFFu + ((u >> 16) & 1u)) >> 16;  // RNE
  return (u16)r;
}
__device__ __forceinline__ float bf2f(u16 h) {
  return __uint_as_float(((u32)h) << 16);
}

__device__ __forceinline__ f32x4 mfma16x16x32(short8 a, short8 b, f32x4 c) {
  return __builtin_amdgcn_mfma_f32_16x16x32_bf16(
      __builtin_bit_cast(bf16x8, a), __builtin_bit_cast(bf16x8, b), c, 0, 0, 0);
}

__device__ __forceinline__ void gload_lds16(const void* g, void* l) {
  __builtin_amdgcn_global_load_lds(
      (const __attribute__((address_space(1))) void*)g,
      (__attribute__((address_space(3))) void*)l, 16, 0, 0);
}

// ---------------- cast f32 -> bf16 (vectorized, 8 elems/thread) ----------------
__global__ void cast_kernel(const float* __restrict__ src, u16* __restrict__ dst, int n8) {
  int i = blockIdx.x * blockDim.x + threadIdx.x;
  if (i >= n8) return;
  const float* s = src + (size_t)i * 8;
  f32x4 a = *reinterpret_cast<const f32x4*>(s);
  f32x4 b = *reinterpret_cast<const f32x4*>(s + 4);
  short8 o;
  o[0] = (short)f2bf(a[0]); o[1] = (short)f2bf(a[1]);
  o[2] = (short)f2bf(a[2]); o[3] = (short)f2bf(a[3]);
  o[4] = (short)f2bf(b[0]); o[5] = (short)f2bf(b[1]);
  o[6] = (short)f2bf(b[2]); o[7] = (short)f2bf(b[3]);
  *reinterpret_cast<short8*>(dst + (size_t)i * 8) = o;
}

// ---------------- NT GEMM: C[M,N] = A[M,K] * B[N,K]^T, m97 structure ----------------
// M=4096, N=2048, K=2048. 128x128 tile, BK=32, 4 waves (2x2 of 64x64).
template <int OUTF32>
__global__ __launch_bounds__(256) void gemm_nt(const u16* __restrict__ A,
                                               const u16* __restrict__ Bw,
                                               void* __restrict__ Cout) {
  constexpr int K = 2048, N = 2048;
  __shared__ u16 As[128 * 32];
  __shared__ u16 Bs[128 * 32];
  const int t = threadIdx.x;
  const int w = t >> 6, l = t & 63;
  const int bm = blockIdx.x, bn = blockIdx.y;
  const int wm = (w >> 1) * 64, wn = (w & 1) * 64;
  const int lr = l & 15, lg = l >> 4;
  f32x4 acc[4][4] = {};

  for (int kk = 0; kk < K; kk += 32) {
    __syncthreads();
#pragma unroll
    for (int i = 0; i < 2; ++i) {
      int cb = (i * 4 + w) * 64;          // wave-uniform chunk base
      int chunk = cb + l;                 // 0..511, 16B chunks
      int row = chunk >> 2, kc = chunk & 3;
      gload_lds16(A + (size_t)(bm * 128 + row) * K + kk + kc * 8, (u16*)As + cb * 8);
      gload_lds16(Bw + (size_t)(bn * 128 + row) * K + kk + kc * 8, (u16*)Bs + cb * 8);
    }
    __syncthreads();
    short8 af[4], bf[4];
#pragma unroll
    for (int mi = 0; mi < 4; ++mi)
      af[mi] = *reinterpret_cast<const short8*>(&As[(wm + mi * 16 + lr) * 32 + lg * 8]);
#pragma unroll
    for (int ni = 0; ni < 4; ++ni)
      bf[ni] = *reinterpret_cast<const short8*>(&Bs[(wn + ni * 16 + lr) * 32 + lg * 8]);
#pragma unroll
    for (int mi = 0; mi < 4; ++mi)
#pragma unroll
      for (int ni = 0; ni < 4; ++ni)
        acc[mi][ni] = mfma16x16x32(af[mi], bf[ni], acc[mi][ni]);
  }
#pragma unroll
  for (int mi = 0; mi < 4; ++mi)
#pragma unroll
    for (int ni = 0; ni < 4; ++ni)
#pragma unroll
      for (int r = 0; r < 4; ++r) {
        int row = bm * 128 + wm + mi * 16 + lg * 4 + r;
        int col = bn * 128 + wn + ni * 16 + lr;
        float v = acc[mi][ni][r];
        if (OUTF32)
          ((float*)Cout)[(size_t)row * N + col] = v;
        else
          ((u16*)Cout)[(size_t)row * N + col] = f2bf(v);
      }
}

// ---------------- RoPE (in-place, Q and K) ----------------
__global__ void rope_kernel(u32* __restrict__ XQ, u32* __restrict__ XK,
                            const float* __restrict__ cosT, const float* __restrict__ sinT) {
  int p = blockIdx.x * blockDim.x + threadIdx.x;  // pair index, flat elem = 2p
  int i = p & 63;
  int s = (p >> 10) & (SS - 1);
  float c = cosT[s * 64 + i], sn = sinT[s * 64 + i];
  u32 q = XQ[p], k = XK[p];
  float q0 = bf2f((u16)(q & 0xFFFF)), q1 = bf2f((u16)(q >> 16));
  float k0 = bf2f((u16)(k & 0xFFFF)), k1 = bf2f((u16)(k >> 16));
  float oq0 = q0 * c - q1 * sn, oq1 = q0 * sn + q1 * c;
  float ok0 = k0 * c - k1 * sn, ok1 = k0 * sn + k1 * c;
  XQ[p] = (u32)f2bf(oq0) | ((u32)f2bf(oq1) << 16);
  XK[p] = (u32)f2bf(ok0) | ((u32)f2bf(ok1) << 16);
}

// ---------------- Flash attention (causal), 4 waves x 16 q-rows, KVBLK=64 ----------------
__global__ __launch_bounds__(256) void attn_kernel(const u16* __restrict__ XQ,
                                                   const u16* __restrict__ XK,
                                                   const u16* __restrict__ XV,
                                                   u16* __restrict__ AO) {
  __shared__ u16 Ks[64 * 128];    // K tile, rows XOR-swizzled by ((k&7)<<4) on byte offset
  __shared__ u16 Vt[128 * 72];    // V^T tile [d][k], stride 72
  __shared__ u16 Ps[4 * 16 * 72]; // per-wave P [16 q][64 k], stride 72
  const int qt = blockIdx.x, bh = blockIdx.y;
  const int b = bh >> 4, h = bh & 15;
  const int t = threadIdx.x, w = t >> 6, l = t & 63;
  const int lr = l & 15, lg = l >> 4;
  const int qbase = qt * 64 + w * 16;
  const size_t rowbase = (size_t)b * SS;

  short8 qf[4];
  {
    const u16* qp = XQ + (rowbase + qbase + lr) * DD + h * HD + lg * 8;
#pragma unroll
    for (int ks = 0; ks < 4; ++ks)
      qf[ks] = *reinterpret_cast<const short8*>(qp + ks * 32);
  }

  float mr[4] = {-1e30f, -1e30f, -1e30f, -1e30f};
  float lsum[4] = {0.f, 0.f, 0.f, 0.f};
  f32x4 o[8] = {};
  u16* Pw = Ps + w * (16 * 72);

  for (int kvt = 0; kvt <= qt; ++kvt) {
    const int kv0 = kvt * 64;
    __syncthreads();
    // --- stage K via global_load_lds, pre-swizzled source (linear dest) ---
#pragma unroll
    for (int i = 0; i < 4; ++i) {
      int cb = (w * 4 + i) * 64;          // wave-uniform chunk base
      int chunk = cb + l;                  // 0..1023 (16 chunks per 128-elem row)
      int krow = chunk >> 4;
      int kc = chunk & 15;
      int lc = kc ^ (krow & 7);            // inverse swizzle on the source
      gload_lds16(XK + (rowbase + kv0 + krow) * DD + h * HD + lc * 8, (u16*)Ks + cb * 8);
    }
    // --- stage V transposed: thread owns a 4k x 8d block ---
    {
      int k0 = (t >> 4) * 4;   // 0..60
      int d0 = (t & 15) * 8;   // 0..120
      const u16* vp = XV + (rowbase + kv0 + k0) * DD + h * HD + d0;
      short8 r0 = *reinterpret_cast<const short8*>(vp);
      short8 r1 = *reinterpret_cast<const short8*>(vp + DD);
      short8 r2 = *reinterpret_cast<const short8*>(vp + 2 * DD);
      short8 r3 = *reinterpret_cast<const short8*>(vp + 3 * DD);
#pragma unroll
      for (int ii = 0; ii < 8; ++ii) {
        short4_ o4;
        o4[0] = r0[ii]; o4[1] = r1[ii]; o4[2] = r2[ii]; o4[3] = r3[ii];
        *reinterpret_cast<short4_*>(&Vt[(d0 + ii) * 72 + k0]) = o4;
      }
    }
    __syncthreads();

    // --- S = Q K^T (16q x 64k per wave) ---
    f32x4 sf[4];
#pragma unroll
    for (int kt = 0; kt < 4; ++kt) {
      f32x4 a = {};
#pragma unroll
      for (int ks = 0; ks < 4; ++ks) {
        int krow = kt * 16 + lr;
        int inner = (ks * 64 + lg * 16) ^ ((krow & 7) << 4);
        short8 kf = *reinterpret_cast<const short8*>((const char*)Ks + krow * 256 + inner);
        a = mfma16x16x32(qf[ks], kf, a);
      }
      sf[kt] = a;
    }

    const float scale = 0.08838834764831845f;  // 1/sqrt(128)
    const bool diag = (kvt == qt);
    float pb[4][4];
#pragma unroll
    for (int kt = 0; kt < 4; ++kt)
#pragma unroll
      for (int r = 0; r < 4; ++r) {
        float s = sf[kt][r] * scale;
        if (diag) {
          int kg = kv0 + kt * 16 + lr;
          int qg = qbase + lg * 4 + r;
          if (kg > qg) s = -1e30f;
        }
        pb[kt][r] = s;
      }

    // --- online softmax (row stats across the 16 lanes of each lg group) ---
#pragma unroll
    for (int r = 0; r < 4; ++r) {
      float m = fmaxf(fmaxf(pb[0][r], pb[1][r]), fmaxf(pb[2][r], pb[3][r]));
      m = fmaxf(m, __shfl_xor(m, 1));
      m = fmaxf(m, __shfl_xor(m, 2));
      m = fmaxf(m, __shfl_xor(m, 4));
      m = fmaxf(m, __shfl_xor(m, 8));
      float mn = fmaxf(mr[r], m);
      float sc = __expf(mr[r] - mn);
      mr[r] = mn;
      float sum = 0.f;
#pragma unroll
      for (int kt = 0; kt < 4; ++kt) {
        float p = __expf(pb[kt][r] - mn);
        pb[kt][r] = p;
        sum += p;
      }
      sum += __shfl_xor(sum, 1);
      sum += __shfl_xor(sum, 2);
      sum += __shfl_xor(sum, 4);
      sum += __shfl_xor(sum, 8);
      lsum[r] = lsum[r] * sc + sum;
#pragma unroll
      for (int dt = 0; dt < 8; ++dt) o[dt][r] *= sc;
    }

    // --- P -> LDS (bf16), then PV ---
#pragma unroll
    for (int kt = 0; kt < 4; ++kt)
#pragma unroll
      for (int r = 0; r < 4; ++r)
        Pw[(lg * 4 + r) * 72 + kt * 16 + lr] = f2bf(pb[kt][r]);

    short8 pa[2];
#pragma unroll
    for (int ks = 0; ks < 2; ++ks)
      pa[ks] = *reinterpret_cast<const short8*>(&Pw[lr * 72 + ks * 32 + lg * 8]);
#pragma unroll
    for (int dt = 0; dt < 8; ++dt)
#pragma unroll
      for (int ks = 0; ks < 2; ++ks) {
        short8 vf = *reinterpret_cast<const short8*>(&Vt[(dt * 16 + lr) * 72 + ks * 32 + lg * 8]);
        o[dt] = mfma16x16x32(pa[ks], vf, o[dt]);
      }
  }

  // --- epilogue: normalize and store bf16 ---
#pragma unroll
  for (int r = 0; r < 4; ++r) {
    float inv = 1.0f / lsum[r];
    int qg = qbase + lg * 4 + r;
    u16* op = AO + (rowbase + qg) * DD + h * HD + lr;
#pragma unroll
    for (int dt = 0; dt < 8; ++dt)
      op[dt * 16] = f2bf(o[dt][r] * inv);
  }
}

// ---------------- launch ----------------
extern "C" void kernel_launch(void* const* d_in, const int* in_sizes, int n_in,
                              void* d_out, int out_size, void* d_ws, size_t ws_size,
                              hipStream_t stream) {
  const float* x = (const float*)d_in[0];
  const float* wq = (const float*)d_in[1];
  const float* wk = (const float*)d_in[2];
  const float* wv = (const float*)d_in[3];
  const float* wo = (const float*)d_in[4];
  const float* cosT = (const float*)d_in[5];
  const float* sinT = (const float*)d_in[6];
  // d_in[7] = mask (pure causal, re-derived analytically), d_in[8] = start_p (0)

  char* ws = (char*)d_ws;
  u16* xb  = (u16*)(ws);
  u16* wqb = (u16*)(ws + 16777216);
  u16* wkb = (u16*)(ws + 25165824);
  u16* wvb = (u16*)(ws + 33554432);
  u16* wob = (u16*)(ws + 41943040);
  u16* XQ  = (u16*)(ws + 50331648);
  u16* XK  = (u16*)(ws + 67108864);
  u16* XV  = (u16*)(ws + 83886080);
  u16* AO  = (u16*)(ws + 100663296);

  cast_kernel<<<4096, 256, 0, stream>>>(x, xb, 1048576);
  cast_kernel<<<2048, 256, 0, stream>>>(wq, wqb, 524288);
  cast_kernel<<<2048, 256, 0, stream>>>(wk, wkb, 524288);
  cast_kernel<<<2048, 256, 0, stream>>>(wv, wvb, 524288);
  cast_kernel<<<2048, 256, 0, stream>>>(wo, wob, 524288);

  dim3 gg(32, 16);
  gemm_nt<0><<<gg, 256, 0, stream>>>(xb, wqb, XQ);
  gemm_nt<0><<<gg, 256, 0, stream>>>(xb, wkb, XK);
  gemm_nt<0><<<gg, 256, 0, stream>>>(xb, wvb, XV);

  rope_kernel<<<16384, 256, 0, stream>>>((u32*)XQ, (u32*)XK, cosT, sinT);

  attn_kernel<<<dim3(32, 32), 256, 0, stream>>>(XQ, XK, XV, AO);

  gemm_nt<1><<<gg, 256, 0, stream>>>(AO, wob, d_out);
}

// Round 2
// 460.996 us; speedup vs baseline: 1.1075x; 1.1075x over previous
//
#include <hip/hip_runtime.h>
#include <cstdint>
#include <cstddef>

typedef unsigned short u16;
typedef unsigned int u32;
typedef __attribute__((ext_vector_type(8))) short short8;   // 8 bf16 storage
typedef __attribute__((ext_vector_type(4))) short short4_;  // 4 bf16 storage
typedef __attribute__((ext_vector_type(8))) __bf16 bf16x8;  // MFMA operand
typedef __attribute__((ext_vector_type(4))) float f32x4;

#define BB 2
#define SS 2048
#define DD 2048
#define HH 16
#define HD 128

__device__ __forceinline__ u16 f2bf(float x) {
  u32 u = __float_as_uint(x);
  u32 r = (u + 0x7FFFu + ((u >> 16) & 1u)) >> 16;  // RNE
  return (u16)r;
}
__device__ __forceinline__ float bf2f(u16 h) {
  return __uint_as_float(((u32)h) << 16);
}

__device__ __forceinline__ f32x4 mfma16x16x32(short8 a, short8 b, f32x4 c) {
  return __builtin_amdgcn_mfma_f32_16x16x32_bf16(
      __builtin_bit_cast(bf16x8, a), __builtin_bit_cast(bf16x8, b), c, 0, 0, 0);
}

__device__ __forceinline__ void gload_lds16(const void* g, void* l) {
  __builtin_amdgcn_global_load_lds(
      (const __attribute__((address_space(1))) void*)g,
      (__attribute__((address_space(3))) void*)l, 16, 0, 0);
}

// ---------------- cast f32 -> bf16 (vectorized, 8 elems/thread) ----------------
__global__ void cast_kernel(const float* __restrict__ src, u16* __restrict__ dst, int n8) {
  int i = blockIdx.x * blockDim.x + threadIdx.x;
  if (i >= n8) return;
  const float* s = src + (size_t)i * 8;
  f32x4 a = *reinterpret_cast<const f32x4*>(s);
  f32x4 b = *reinterpret_cast<const f32x4*>(s + 4);
  short8 o;
  o[0] = (short)f2bf(a[0]); o[1] = (short)f2bf(a[1]);
  o[2] = (short)f2bf(a[2]); o[3] = (short)f2bf(a[3]);
  o[4] = (short)f2bf(b[0]); o[5] = (short)f2bf(b[1]);
  o[6] = (short)f2bf(b[2]); o[7] = (short)f2bf(b[3]);
  *reinterpret_cast<short8*>(dst + (size_t)i * 8) = o;
}

// ---------------- NT GEMM: C[M,N] = A[M,K] * B[N,K]^T, m97 structure ----------------
template <int OUTF32>
__global__ __launch_bounds__(256) void gemm_nt(const u16* __restrict__ A,
                                               const u16* __restrict__ Bw,
                                               void* __restrict__ Cout) {
  constexpr int K = 2048, N = 2048;
  __shared__ u16 As[128 * 32];
  __shared__ u16 Bs[128 * 32];
  const int t = threadIdx.x;
  const int w = t >> 6, l = t & 63;
  const int bm = blockIdx.x, bn = blockIdx.y;
  const int wm = (w >> 1) * 64, wn = (w & 1) * 64;
  const int lr = l & 15, lg = l >> 4;
  f32x4 acc[4][4] = {};

  for (int kk = 0; kk < K; kk += 32) {
    __syncthreads();
#pragma unroll
    for (int i = 0; i < 2; ++i) {
      int cb = (i * 4 + w) * 64;
      int chunk = cb + l;
      int row = chunk >> 2, kc = chunk & 3;
      gload_lds16(A + (size_t)(bm * 128 + row) * K + kk + kc * 8, (u16*)As + cb * 8);
      gload_lds16(Bw + (size_t)(bn * 128 + row) * K + kk + kc * 8, (u16*)Bs + cb * 8);
    }
    __syncthreads();
    short8 af[4], bf[4];
#pragma unroll
    for (int mi = 0; mi < 4; ++mi)
      af[mi] = *reinterpret_cast<const short8*>(&As[(wm + mi * 16 + lr) * 32 + lg * 8]);
#pragma unroll
    for (int ni = 0; ni < 4; ++ni)
      bf[ni] = *reinterpret_cast<const short8*>(&Bs[(wn + ni * 16 + lr) * 32 + lg * 8]);
#pragma unroll
    for (int mi = 0; mi < 4; ++mi)
#pragma unroll
      for (int ni = 0; ni < 4; ++ni)
        acc[mi][ni] = mfma16x16x32(af[mi], bf[ni], acc[mi][ni]);
  }
#pragma unroll
  for (int mi = 0; mi < 4; ++mi)
#pragma unroll
    for (int ni = 0; ni < 4; ++ni)
#pragma unroll
      for (int r = 0; r < 4; ++r) {
        int row = bm * 128 + wm + mi * 16 + lg * 4 + r;
        int col = bn * 128 + wn + ni * 16 + lr;
        float v = acc[mi][ni][r];
        if (OUTF32)
          ((float*)Cout)[(size_t)row * N + col] = v;
        else
          ((u16*)Cout)[(size_t)row * N + col] = f2bf(v);
      }
}

// ---------------- RoPE (in-place, Q and K) ----------------
__global__ void rope_kernel(u32* __restrict__ XQ, u32* __restrict__ XK,
                            const float* __restrict__ cosT, const float* __restrict__ sinT) {
  int p = blockIdx.x * blockDim.x + threadIdx.x;
  int i = p & 63;
  int s = (p >> 10) & (SS - 1);
  float c = cosT[s * 64 + i], sn = sinT[s * 64 + i];
  u32 q = XQ[p], k = XK[p];
  float q0 = bf2f((u16)(q & 0xFFFF)), q1 = bf2f((u16)(q >> 16));
  float k0 = bf2f((u16)(k & 0xFFFF)), k1 = bf2f((u16)(k >> 16));
  float oq0 = q0 * c - q1 * sn, oq1 = q0 * sn + q1 * c;
  float ok0 = k0 * c - k1 * sn, ok1 = k0 * sn + k1 * c;
  XQ[p] = (u32)f2bf(oq0) | ((u32)f2bf(oq1) << 16);
  XK[p] = (u32)f2bf(ok0) | ((u32)f2bf(ok1) << 16);
}

// ---------------- Flash attention (causal), paired q-tiles, double-buffered ----------------
// Block = 256 threads (4 waves x 16 q-rows per tile). blockIdx.x = i pairs
// q-tiles (i, 31-i): shared K/V staging, every block does exactly 33 tile-computes.
// K: linear LDS via global_load_lds with pre-swizzled source (byte ^ ((krow&7)<<4)).
// Vt: [d=128][k=64], byte ^ ((((d>>3)&7)^(d&7))<<4)  -> ~2-way write conflicts.
__global__ __launch_bounds__(256, 2) void attn_kernel(const u16* __restrict__ XQ,
                                                      const u16* __restrict__ XK,
                                                      const u16* __restrict__ XV,
                                                      u16* __restrict__ AO) {
  __shared__ u16 Ks[2][64 * 128];
  __shared__ u16 Vs[2][128 * 64];
  __shared__ u16 Ps[4][16 * 72];
  const int ip = blockIdx.x, bh = blockIdx.y;
  const int b = bh >> 4, h = bh & 15;
  const int qtA = ip, qtB = 31 - ip;
  const int t = threadIdx.x, w = t >> 6, l = t & 63;
  const int lr = l & 15, lg = l >> 4;
  const size_t rowbase = (size_t)b * SS;
  const int qbA = qtA * 64 + w * 16;
  const int qbB = qtB * 64 + w * 16;

  short8 qfA[4], qfB[4];
  {
    const u16* qpA = XQ + (rowbase + qbA + lr) * DD + h * HD + lg * 8;
    const u16* qpB = XQ + (rowbase + qbB + lr) * DD + h * HD + lg * 8;
#pragma unroll
    for (int ks = 0; ks < 4; ++ks) {
      qfA[ks] = *reinterpret_cast<const short8*>(qpA + ks * 32);
      qfB[ks] = *reinterpret_cast<const short8*>(qpB + ks * 32);
    }
  }

  f32x4 oA[8] = {}, oB[8] = {};
  float mrA[4], mrB[4], lsA[4], lsB[4];
#pragma unroll
  for (int r = 0; r < 4; ++r) { mrA[r] = -1e30f; mrB[r] = -1e30f; lsA[r] = 0.f; lsB[r] = 0.f; }

  u16* Pw = Ps[w];
  short8 vr[4];
  const int vk0 = (t >> 4) * 4;   // 0..60
  const int vd0 = (t & 15) * 8;   // 0..120

  auto issueK = [&](int kvt, int buf) {
#pragma unroll
    for (int i2 = 0; i2 < 4; ++i2) {
      int cb = (w * 4 + i2) * 64;
      int chunk = cb + l;
      int krow = chunk >> 4, kc = chunk & 15;
      int lc = kc ^ (krow & 7);
      gload_lds16(XK + (rowbase + kvt * 64 + krow) * DD + h * HD + lc * 8,
                  (u16*)Ks[buf] + cb * 8);
    }
  };
  auto loadV = [&](int kvt) {
    const u16* vp = XV + (rowbase + kvt * 64 + vk0) * DD + h * HD + vd0;
#pragma unroll
    for (int r = 0; r < 4; ++r) vr[r] = *reinterpret_cast<const short8*>(vp + r * DD);
  };
  auto writeV = [&](int buf) {
    char* base = (char*)Vs[buf];
#pragma unroll
    for (int ii = 0; ii < 8; ++ii) {
      int d = vd0 + ii;
      int off = d * 128 + ((vk0 * 2) ^ ((((d >> 3) & 7) ^ (d & 7)) << 4));
      short4_ o4;
      o4[0] = vr[0][ii]; o4[1] = vr[1][ii]; o4[2] = vr[2][ii]; o4[3] = vr[3][ii];
      *reinterpret_cast<short4_*>(base + off) = o4;
    }
  };

  auto softmax_pv = [&](int kv, int cur, f32x4* sf, float* mr, float* ls, f32x4* o, int qbase) {
    const float scale = 0.08838834764831845f;  // 1/sqrt(128)
    const bool diag = (kv == (qbase >> 6));
    const int kv0 = kv * 64;
    float pb[4][4];
#pragma unroll
    for (int kt = 0; kt < 4; ++kt)
#pragma unroll
      for (int r = 0; r < 4; ++r) {
        float s = sf[kt][r] * scale;
        if (diag) {
          int kg = kv0 + kt * 16 + lr;
          int qg = qbase + lg * 4 + r;
          if (kg > qg) s = -1e30f;
        }
        pb[kt][r] = s;
      }
#pragma unroll
    for (int r = 0; r < 4; ++r) {
      float m = fmaxf(fmaxf(pb[0][r], pb[1][r]), fmaxf(pb[2][r], pb[3][r]));
      m = fmaxf(m, __shfl_xor(m, 1));
      m = fmaxf(m, __shfl_xor(m, 2));
      m = fmaxf(m, __shfl_xor(m, 4));
      m = fmaxf(m, __shfl_xor(m, 8));
      float mn = fmaxf(mr[r], m);
      float sc = __expf(mr[r] - mn);
      mr[r] = mn;
      float sum = 0.f;
#pragma unroll
      for (int kt = 0; kt < 4; ++kt) {
        float p = __expf(pb[kt][r] - mn);
        pb[kt][r] = p;
        sum += p;
      }
      sum += __shfl_xor(sum, 1);
      sum += __shfl_xor(sum, 2);
      sum += __shfl_xor(sum, 4);
      sum += __shfl_xor(sum, 8);
      ls[r] = ls[r] * sc + sum;
#pragma unroll
      for (int dt = 0; dt < 8; ++dt) o[dt][r] *= sc;
    }
#pragma unroll
    for (int kt = 0; kt < 4; ++kt)
#pragma unroll
      for (int r = 0; r < 4; ++r)
        Pw[(lg * 4 + r) * 72 + kt * 16 + lr] = f2bf(pb[kt][r]);
    short8 pa[2];
#pragma unroll
    for (int ks = 0; ks < 2; ++ks)
      pa[ks] = *reinterpret_cast<const short8*>(&Pw[lr * 72 + ks * 32 + lg * 8]);
    const char* vbase = (const char*)Vs[cur];
#pragma unroll
    for (int dt = 0; dt < 8; ++dt)
#pragma unroll
      for (int ks = 0; ks < 2; ++ks) {
        int d = dt * 16 + lr;
        int off = d * 128 + ((ks * 64 + lg * 16) ^ ((((d >> 3) & 7) ^ (d & 7)) << 4));
        short8 vf = *reinterpret_cast<const short8*>(vbase + off);
        o[dt] = mfma16x16x32(pa[ks], vf, o[dt]);
      }
  };

  // prologue: stage tile 0
  issueK(0, 0);
  loadV(0);

  for (int kv = 0; kv <= qtB; ++kv) {
    const int cur = kv & 1;
    writeV(cur);
    __syncthreads();   // drains vmcnt: K[cur] LDS-resident; Vs[cur] writes visible
    if (kv < qtB) { issueK(kv + 1, cur ^ 1); loadV(kv + 1); }

    const bool doA = (kv <= qtA);
    f32x4 sB[4], sA[4];
#pragma unroll
    for (int kt = 0; kt < 4; ++kt) {
      sB[kt] = f32x4{0.f, 0.f, 0.f, 0.f};
      sA[kt] = f32x4{0.f, 0.f, 0.f, 0.f};
    }
#pragma unroll
    for (int kt = 0; kt < 4; ++kt) {
      short8 kf[4];
#pragma unroll
      for (int ks = 0; ks < 4; ++ks) {
        int krow = kt * 16 + lr;
        int inner = (ks * 64 + lg * 16) ^ ((krow & 7) << 4);
        kf[ks] = *reinterpret_cast<const short8*>((const char*)Ks[cur] + krow * 256 + inner);
      }
#pragma unroll
      for (int ks = 0; ks < 4; ++ks) sB[kt] = mfma16x16x32(qfB[ks], kf[ks], sB[kt]);
      if (doA) {
#pragma unroll
        for (int ks = 0; ks < 4; ++ks) sA[kt] = mfma16x16x32(qfA[ks], kf[ks], sA[kt]);
      }
    }
    softmax_pv(kv, cur, sB, mrB, lsB, oB, qbB);
    if (doA) softmax_pv(kv, cur, sA, mrA, lsA, oA, qbA);
  }

  // epilogue
#pragma unroll
  for (int r = 0; r < 4; ++r) {
    float invB = 1.0f / lsB[r];
    float invA = 1.0f / lsA[r];
    int qgB = qbB + lg * 4 + r;
    int qgA = qbA + lg * 4 + r;
    u16* opB = AO + (rowbase + qgB) * DD + h * HD + lr;
    u16* opA = AO + (rowbase + qgA) * DD + h * HD + lr;
#pragma unroll
    for (int dt = 0; dt < 8; ++dt) {
      opB[dt * 16] = f2bf(oB[dt][r] * invB);
      opA[dt * 16] = f2bf(oA[dt][r] * invA);
    }
  }
}

// ---------------- launch ----------------
extern "C" void kernel_launch(void* const* d_in, const int* in_sizes, int n_in,
                              void* d_out, int out_size, void* d_ws, size_t ws_size,
                              hipStream_t stream) {
  const float* x = (const float*)d_in[0];
  const float* wq = (const float*)d_in[1];
  const float* wk = (const float*)d_in[2];
  const float* wv = (const float*)d_in[3];
  const float* wo = (const float*)d_in[4];
  const float* cosT = (const float*)d_in[5];
  const float* sinT = (const float*)d_in[6];

  char* ws = (char*)d_ws;
  u16* xb  = (u16*)(ws);
  u16* wqb = (u16*)(ws + 16777216);
  u16* wkb = (u16*)(ws + 25165824);
  u16* wvb = (u16*)(ws + 33554432);
  u16* wob = (u16*)(ws + 41943040);
  u16* XQ  = (u16*)(ws + 50331648);
  u16* XK  = (u16*)(ws + 67108864);
  u16* XV  = (u16*)(ws + 83886080);
  u16* AO  = (u16*)(ws + 100663296);

  cast_kernel<<<4096, 256, 0, stream>>>(x, xb, 1048576);
  cast_kernel<<<2048, 256, 0, stream>>>(wq, wqb, 524288);
  cast_kernel<<<2048, 256, 0, stream>>>(wk, wkb, 524288);
  cast_kernel<<<2048, 256, 0, stream>>>(wv, wvb, 524288);
  cast_kernel<<<2048, 256, 0, stream>>>(wo, wob, 524288);

  dim3 gg(32, 16);
  gemm_nt<0><<<gg, 256, 0, stream>>>(xb, wqb, XQ);
  gemm_nt<0><<<gg, 256, 0, stream>>>(xb, wkb, XK);
  gemm_nt<0><<<gg, 256, 0, stream>>>(xb, wvb, XV);

  rope_kernel<<<16384, 256, 0, stream>>>((u32*)XQ, (u32*)XK, cosT, sinT);

  attn_kernel<<<dim3(16, 32), 256, 0, stream>>>(XQ, XK, XV, AO);

  gemm_nt<1><<<gg, 256, 0, stream>>>(AO, wob, d_out);
}